// Round 5
// baseline (352.471 us; speedup 1.0000x reference)
//
#include <hip/hip_runtime.h>
#include <math.h>

#define NB 16
#define NL 1024
#define NH 8
#define NE 64
#define NWIN 1024
#define NG 64

#define SCH 128     // s-chunk / l-chunk per block
#define SROW 136    // sb row stride in shorts (16B-aligned)

typedef __attribute__((ext_vector_type(8))) short short8;
typedef __attribute__((ext_vector_type(4))) float floatx4;

__device__ __forceinline__ short f2bf(float x) {
    unsigned u = __float_as_uint(x);
    u += 0x7fffu + ((u >> 16) & 1u);   // round-to-nearest-even
    return (short)(u >> 16);
}
__device__ __forceinline__ float dot4(float4 a, float4 b) {
    return fmaf(a.x, b.x, fmaf(a.y, b.y, fmaf(a.z, b.z, a.w * b.w)));
}
// Orders LDS traffic without draining vmcnt (keeps prefetch in flight).
__device__ __forceinline__ void lgkm_barrier() {
    asm volatile("s_waitcnt lgkmcnt(0)" ::: "memory");
    __builtin_amdgcn_s_barrier();
}

// Fused sel+attention, REGULAR launch (graph-capturable), per-bh flag sync.
// grid = 1024 = 256 CU x 4 blocks; LDS 35328 B and launch_bounds(256,4)
// guarantee exactly-full co-residency -> the flag spin cannot deadlock.
// Block (bh, ee): sel-MLP + qp/qn partial for l in [ee*128,+128); release
// flag; spin until all 8 ee-blocks of this bh released; then attention for
// s-chunk [ee*128,+128). k/v tiles prefetched to registers before the spin.
__global__ __launch_bounds__(256, 4) void k_fused(
    const float* __restrict__ x, const float* __restrict__ mlp_w,
    const float* __restrict__ mlp_b, const float* __restrict__ q,
    const float* __restrict__ keys, const float* __restrict__ values,
    const float* __restrict__ sel_W,
    float* __restrict__ qp, float* __restrict__ qn,
    int* __restrict__ cnt, float* __restrict__ out)
{
    // manual aliasing: [0,32768) = w_lds, reused post-MLP for attn buffers
    __shared__ __align__(16) char smem[35328];
    float4 (*w_lds)[NWIN / 4] = (float4(*)[NWIN / 4])smem;          // [8][256]
    float*  t_lds             = (float*)(smem + 32768);             // 128 f
    float  (*redp)[64]        = (float(*)[64])(smem + 33280);       // [4][64]
    float  (*redn)[64]        = (float(*)[64])(smem + 34304);       // [4][64]
    // attention-phase views (alias the dead w_lds region):
    short  (*sb)[SROW]        = (short(*)[SROW])smem;               // 17408 B
    float*  ap_l              = (float*)(smem + 17408);
    float*  an_l              = (float*)(smem + 17920);
    float2* wpn               = (float2*)(smem + 18432);
    float  (*mx2)[SCH]        = (float(*)[SCH])(smem + 18944);
    float  (*dn2)[SCH]        = (float(*)[SCH])(smem + 19968);
    float*  qp_l              = (float*)(smem + 20992);             // 64 f
    float*  qn_l              = (float*)(smem + 21248);             // ends 21504

    int tid = threadIdx.x, blk = blockIdx.x;
    int ee = blk & 7, bh = blk >> 3;
    int b = bh >> 3, h = bh & 7;
    int w = tid >> 6, lane = tid & 63;
    int sq = lane >> 4, c = lane & 15;
    const float scale = 0.125f;             // 1/sqrt(64)
    int s0 = ee * SCH;

    // ---- stage mlp_w (32 KB) ----
    {
        const float4* w4 = (const float4*)mlp_w;
        float4* wl = (float4*)smem;
        #pragma unroll
        for (int i = 0; i < 8; ++i)
            wl[tid + 256 * i] = w4[tid + 256 * i];
    }
    __syncthreads();

    // ---- phase 1: tanh-MLP, one row per 16-lane group (16 rows/block) ----
    {
        int row_loc = w * 4 + sq;                               // [0,16)
        int r = b * 1024 + h * 128 + ee * 16 + row_loc;
        const float4* xr = (const float4*)(x + (size_t)r * NWIN);
        float4 a03 = make_float4(0,0,0,0), a47 = make_float4(0,0,0,0);
        #pragma unroll
        for (int i = 0; i < 16; ++i) {
            float4 xv = xr[i * 16 + c];
            a03.x += dot4(xv, w_lds[0][i * 16 + c]);
            a03.y += dot4(xv, w_lds[1][i * 16 + c]);
            a03.z += dot4(xv, w_lds[2][i * 16 + c]);
            a03.w += dot4(xv, w_lds[3][i * 16 + c]);
            a47.x += dot4(xv, w_lds[4][i * 16 + c]);
            a47.y += dot4(xv, w_lds[5][i * 16 + c]);
            a47.z += dot4(xv, w_lds[6][i * 16 + c]);
            a47.w += dot4(xv, w_lds[7][i * 16 + c]);
        }
        #pragma unroll
        for (int off = 1; off < 16; off <<= 1) {
            a03.x += __shfl_xor(a03.x, off, 64);
            a03.y += __shfl_xor(a03.y, off, 64);
            a03.z += __shfl_xor(a03.z, off, 64);
            a03.w += __shfl_xor(a03.w, off, 64);
            a47.x += __shfl_xor(a47.x, off, 64);
            a47.y += __shfl_xor(a47.y, off, 64);
            a47.z += __shfl_xor(a47.z, off, 64);
            a47.w += __shfl_xor(a47.w, off, 64);
        }
        if (c == 0) {
            float4 b03 = *(const float4*)mlp_b;
            float4 b47 = *(const float4*)(mlp_b + 4);
            float4 t03, t47;
            t03.x = tanhf(a03.x + b03.x); t03.y = tanhf(a03.y + b03.y);
            t03.z = tanhf(a03.z + b03.z); t03.w = tanhf(a03.w + b03.w);
            t47.x = tanhf(a47.x + b47.x); t47.y = tanhf(a47.y + b47.y);
            t47.z = tanhf(a47.z + b47.z); t47.w = tanhf(a47.w + b47.w);
            *(float4*)&t_lds[row_loc * 8]     = t03;
            *(float4*)&t_lds[row_loc * 8 + 4] = t47;
        }
    }
    lgkm_barrier();   // t ready; w_lds reads done -> region reusable

    // wpn (dead w_lds region, read after the flag wait)
    if (tid < NG) {
        float W = sel_W[h * NG + tid];
        wpn[tid] = make_float2(fmaxf(W, 0.f) * scale, fminf(W, 0.f) * scale);
    }

    // k prefetch for phase A (completes during phase 2 / spin)
    float4 kvv[8];
    #pragma unroll
    for (int p = 0; p < 8; ++p) {
        int sl = w * 32 + p * 4 + sq;
        kvv[p] = *(const float4*)(keys + (((size_t)(b * NL + s0 + sl)) * NH + h) * NE + c * 4);
    }

    // ---- phase 2: qp/qn partial over l in [ee*128,+128) ----
    {
        int lo = sq, e4 = c;
        float4 accp = make_float4(0,0,0,0), accn = make_float4(0,0,0,0);
        #pragma unroll
        for (int i = 0; i < 8; ++i) {
            int l_loc = w * 32 + i * 4 + lo;
            float tv = t_lds[l_loc];
            int l = ee * 128 + l_loc;
            float4 qv = *(const float4*)(q + (((size_t)(b * NL + l)) * NH + h) * NE + e4 * 4);
            float tp = fmaxf(tv, 0.f), tn = fminf(tv, 0.f);
            accp.x = fmaf(tp, qv.x, accp.x); accp.y = fmaf(tp, qv.y, accp.y);
            accp.z = fmaf(tp, qv.z, accp.z); accp.w = fmaf(tp, qv.w, accp.w);
            accn.x = fmaf(tn, qv.x, accn.x); accn.y = fmaf(tn, qv.y, accn.y);
            accn.z = fmaf(tn, qv.z, accn.z); accn.w = fmaf(tn, qv.w, accn.w);
        }
        #pragma unroll
        for (int off = 16; off <= 32; off <<= 1) {
            accp.x += __shfl_xor(accp.x, off, 64); accp.y += __shfl_xor(accp.y, off, 64);
            accp.z += __shfl_xor(accp.z, off, 64); accp.w += __shfl_xor(accp.w, off, 64);
            accn.x += __shfl_xor(accn.x, off, 64); accn.y += __shfl_xor(accn.y, off, 64);
            accn.z += __shfl_xor(accn.z, off, 64); accn.w += __shfl_xor(accn.w, off, 64);
        }
        if (lo == 0) {
            *(float4*)&redp[w][e4 * 4] = accp;
            *(float4*)&redn[w][e4 * 4] = accn;
        }
    }
    lgkm_barrier();   // redp/redn visible

    // global qp/qn accumulate, then release this block's flag
    if (tid < 64) {
        atomicAdd(&qp[bh * NE + tid], redp[0][tid] + redp[1][tid] + redp[2][tid] + redp[3][tid]);
    } else if (tid < 128) {
        int e = tid - 64;
        atomicAdd(&qn[bh * NE + e], redn[0][e] + redn[1][e] + redn[2][e] + redn[3][e]);
    }
    if (tid < 128) __threadfence();          // producers' atomics device-visible
    __builtin_amdgcn_s_barrier();
    if (tid == 0)
        __hip_atomic_fetch_add(&cnt[bh], 1, __ATOMIC_RELEASE, __HIP_MEMORY_SCOPE_AGENT);

    // v prefetch for phase C — issued now so it flies through the spin
    const float* vbase = values + (((size_t)(b * NL + s0)) * NH + h) * NE + 16 * w + c;
    float vregA[16], vregB[16];
    #pragma unroll
    for (int m = 0; m < 16; ++m)
        vregA[m] = vbase[(size_t)((m >> 3) * 32 + sq * 8 + (m & 7)) * (NH * NE)];
    #pragma unroll
    for (int m = 0; m < 16; ++m)
        vregB[m] = vbase[(size_t)((2 + (m >> 3)) * 32 + sq * 8 + (m & 7)) * (NH * NE)];
    __builtin_amdgcn_sched_barrier(0);

    // wait for all 8 ee-blocks of this bh
    if (tid == 0) {
        while (__hip_atomic_load(&cnt[bh], __ATOMIC_ACQUIRE, __HIP_MEMORY_SCOPE_AGENT) < 8)
            __builtin_amdgcn_s_sleep(2);
    }
    __builtin_amdgcn_s_barrier();

    // coherent qp/qn -> LDS (device-scope loads: per-XCD L2 not cross-coherent)
    if (tid < 64) {
        qp_l[tid] = __hip_atomic_load(&qp[bh * NE + tid], __ATOMIC_RELAXED, __HIP_MEMORY_SCOPE_AGENT);
    } else if (tid < 128) {
        qn_l[tid - 64] = __hip_atomic_load(&qn[bh * NE + (tid - 64)], __ATOMIC_RELAXED, __HIP_MEMORY_SCOPE_AGENT);
    }
    lgkm_barrier();

    // ---- attention ----
    const float4 qp4 = *(const float4*)&qp_l[c * 4];
    const float4 qn4 = *(const float4*)&qn_l[c * 4];

    // phase A: ap/an from the prefetched k tile
    #pragma unroll
    for (int p = 0; p < 8; ++p) {
        int sl = w * 32 + p * 4 + sq;
        float pp = dot4(kvv[p], qp4);
        float pn = dot4(kvv[p], qn4);
        #pragma unroll
        for (int m_ = 1; m_ <= 8; m_ <<= 1) {
            pp += __shfl_xor(pp, m_, 64);
            pn += __shfl_xor(pn, m_, 64);
        }
        if (c == 0) { ap_l[sl] = pp; an_l[sl] = pn; }
    }
    lgkm_barrier();

    // phase B: softmax over g, g-range split across thread halves
    {
        int s_ = tid & 127, gh = tid >> 7, g0 = gh * 32;
        float ap = ap_l[s_], an = an_l[s_];
        float m = -1e30f;
        #pragma unroll 8
        for (int g = 0; g < 32; ++g) {
            float2 wv = wpn[g0 + g];
            m = fmaxf(m, fmaf(wv.x, ap, wv.y * an));
        }
        mx2[gh][s_] = m;
        lgkm_barrier();
        m = fmaxf(mx2[0][s_], mx2[1][s_]);
        float d = 0.f;
        #pragma unroll 8
        for (int g = 0; g < 32; ++g) {
            float2 wv = wpn[g0 + g];
            d += __expf(fmaf(wv.x, ap, wv.y * an) - m);
        }
        dn2[gh][s_] = d;
        lgkm_barrier();
        float inv = 1.0f / (dn2[0][s_] + dn2[1][s_]);
        #pragma unroll 8
        for (int g = 0; g < 32; ++g) {
            float2 wv = wpn[g0 + g];
            sb[g0 + g][s_] = f2bf(__expf(fmaf(wv.x, ap, wv.y * an) - m) * inv);
        }
    }
    lgkm_barrier();

    // phase C: MFMA, wave owns e-tile [16w, 16w+16)
    floatx4 acc[4] = {{0.f,0.f,0.f,0.f},{0.f,0.f,0.f,0.f},
                      {0.f,0.f,0.f,0.f},{0.f,0.f,0.f,0.f}};
    #pragma unroll
    for (int ks = 0; ks < 4; ++ks) {
        short8 av;
        #pragma unroll
        for (int j = 0; j < 8; ++j)
            av[j] = f2bf(ks < 2 ? vregA[ks * 8 + j] : vregB[(ks - 2) * 8 + j]);
        #pragma unroll
        for (int n = 0; n < 4; ++n) {
            short8 bv = *(const short8*)&sb[16 * n + c][ks * 32 + sq * 8];
            acc[n] = __builtin_amdgcn_mfma_f32_16x16x32_bf16(av, bv, acc[n], 0, 0, 0);
        }
    }

    // epilogue: D[row=sq*4+r][col=c]; 8 chunk-blocks accumulate per (b,h)
    #pragma unroll
    for (int n = 0; n < 4; ++n) {
        #pragma unroll
        for (int r_ = 0; r_ < 4; ++r_) {
            int e = 16 * w + sq * 4 + r_;
            int g = 16 * n + c;
            atomicAdd(&out[((size_t)(b * NE + e) * NH + h) * NG + g], acc[n][r_]);
        }
    }
}

extern "C" void kernel_launch(void* const* d_in, const int* in_sizes, int n_in,
                              void* d_out, int out_size, void* d_ws, size_t ws_size,
                              hipStream_t stream) {
    (void)in_sizes; (void)n_in; (void)ws_size;
    const float* queries = (const float*)d_in[0];
    const float* keys    = (const float*)d_in[1];
    const float* values  = (const float*)d_in[2];
    const float* x       = (const float*)d_in[3];
    const float* mlp_w   = (const float*)d_in[4];
    const float* mlp_b   = (const float*)d_in[5];
    const float* sel_W   = (const float*)d_in[6];
    float* out = (float*)d_out;

    // ws layout: qp[8192] f32 | qn[8192] f32 | cnt[128] i32
    float* qp_ws = (float*)d_ws;
    float* qn_ws = qp_ws + NB * NH * NE;
    int*   cnt   = (int*)(qn_ws + NB * NH * NE);

    hipMemsetAsync(out, 0, (size_t)out_size * sizeof(float), stream);
    hipMemsetAsync(qp_ws, 0,
                   (size_t)2 * NB * NH * NE * sizeof(float) + NB * NH * sizeof(int),
                   stream);

    k_fused<<<dim3(NB * NH * 8), dim3(256), 0, stream>>>(
        x, mlp_w, mlp_b, queries, keys, values, sel_W, qp_ws, qn_ws, cnt, out);
}

// Round 6
// 199.645 us; speedup vs baseline: 1.7655x; 1.7655x over previous
//
#include <hip/hip_runtime.h>
#include <math.h>

#define NB 16
#define NL 1024
#define NH 8
#define NE 64
#define NWIN 1024
#define NG 64

#define SCH 128     // s-chunk per block in k_attn_out
#define SROW 136    // sb row stride in shorts (16B-aligned)

typedef __attribute__((ext_vector_type(8))) short short8;
typedef __attribute__((ext_vector_type(4))) float floatx4;

__device__ __forceinline__ short f2bf(float x) {
    unsigned u = __float_as_uint(x);
    u += 0x7fffu + ((u >> 16) & 1u);   // round-to-nearest-even
    return (short)(u >> 16);
}
__device__ __forceinline__ float dot4(float4 a, float4 b) {
    return fmaf(a.x, b.x, fmaf(a.y, b.y, fmaf(a.z, b.z, a.w * b.w)));
}
// Orders LDS traffic without draining vmcnt (keeps prefetch in flight).
__device__ __forceinline__ void lgkm_barrier() {
    asm volatile("s_waitcnt lgkmcnt(0)" ::: "memory");
    __builtin_amdgcn_s_barrier();
}
// Wave-local LDS RAW fence (no cross-wave barrier).
__device__ __forceinline__ void lgkm_wait() {
    asm volatile("s_waitcnt lgkmcnt(0)" ::: "memory");
}

// Fused kernel: tanh-MLP (t stays in LDS) + qp/qn reduction.
// v6: phase1->phase2 dependency is wave-local (wave w computes t rows
// [w*4,w*4+4) and consumes exactly those) -> bare lgkmcnt wait, no barrier.
__global__ __launch_bounds__(256, 4) void k_sel_q(
    const float* __restrict__ x, const float* __restrict__ mlp_w,
    const float* __restrict__ mlp_b, const float* __restrict__ q,
    float* __restrict__ qp, float* __restrict__ qn)
{
    __shared__ float4 w_lds[8][NWIN / 4];   // 32 KB
    __shared__ float t_lds[128];
    __shared__ float redp[4][64], redn[4][64];

    int tid = threadIdx.x;
    int blk = blockIdx.x;
    int ee = blk & 7, bh = blk >> 3;
    int b = bh >> 3, h = bh & 7;
    int w = tid >> 6, lane = tid & 63;
    int sq = lane >> 4, c = lane & 15;

    const float4* w4 = (const float4*)mlp_w;
    float4* wl = (float4*)w_lds;
    #pragma unroll
    for (int i = 0; i < 8; ++i)
        wl[tid + 256 * i] = w4[tid + 256 * i];
    __syncthreads();

    // ---- phase 1: tanh-MLP, one row per 16-lane group (16 rows/block) ----
    int row_loc = w * 4 + sq;                               // [0,16)
    int r = b * 1024 + h * 128 + ee * 16 + row_loc;
    const float4* xr = (const float4*)(x + (size_t)r * NWIN);
    float4 a03 = make_float4(0,0,0,0), a47 = make_float4(0,0,0,0);
    #pragma unroll
    for (int i = 0; i < 16; ++i) {
        float4 xv = xr[i * 16 + c];
        a03.x += dot4(xv, w_lds[0][i * 16 + c]);
        a03.y += dot4(xv, w_lds[1][i * 16 + c]);
        a03.z += dot4(xv, w_lds[2][i * 16 + c]);
        a03.w += dot4(xv, w_lds[3][i * 16 + c]);
        a47.x += dot4(xv, w_lds[4][i * 16 + c]);
        a47.y += dot4(xv, w_lds[5][i * 16 + c]);
        a47.z += dot4(xv, w_lds[6][i * 16 + c]);
        a47.w += dot4(xv, w_lds[7][i * 16 + c]);
    }
    // 4-level butterfly within the 16-lane group
    #pragma unroll
    for (int off = 1; off < 16; off <<= 1) {
        a03.x += __shfl_xor(a03.x, off, 64);
        a03.y += __shfl_xor(a03.y, off, 64);
        a03.z += __shfl_xor(a03.z, off, 64);
        a03.w += __shfl_xor(a03.w, off, 64);
        a47.x += __shfl_xor(a47.x, off, 64);
        a47.y += __shfl_xor(a47.y, off, 64);
        a47.z += __shfl_xor(a47.z, off, 64);
        a47.w += __shfl_xor(a47.w, off, 64);
    }
    if (c == 0) {
        float4 b03 = *(const float4*)mlp_b;
        float4 b47 = *(const float4*)(mlp_b + 4);
        float4 t03, t47;
        t03.x = tanhf(a03.x + b03.x); t03.y = tanhf(a03.y + b03.y);
        t03.z = tanhf(a03.z + b03.z); t03.w = tanhf(a03.w + b03.w);
        t47.x = tanhf(a47.x + b47.x); t47.y = tanhf(a47.y + b47.y);
        t47.z = tanhf(a47.z + b47.z); t47.w = tanhf(a47.w + b47.w);
        *(float4*)&t_lds[row_loc * 8]     = t03;
        *(float4*)&t_lds[row_loc * 8 + 4] = t47;
    }
    lgkm_wait();   // wave-local: wave w wrote rows [w*4,w*4+4), reads same

    // ---- phase 2: qp/qn partial over l in [ee*128, ee*128+128) ----
    int lo = sq, e4 = c;
    float4 accp = make_float4(0,0,0,0), accn = make_float4(0,0,0,0);
    #pragma unroll
    for (int i = 0; i < 8; ++i) {
        int l_loc = w * 32 + i * 4 + lo;
        float tv = t_lds[l_loc];
        int l = ee * 128 + l_loc;
        float4 qv = *(const float4*)(q + (((size_t)(b * NL + l)) * NH + h) * NE + e4 * 4);
        float tp = fmaxf(tv, 0.f), tn = fminf(tv, 0.f);
        accp.x = fmaf(tp, qv.x, accp.x); accp.y = fmaf(tp, qv.y, accp.y);
        accp.z = fmaf(tp, qv.z, accp.z); accp.w = fmaf(tp, qv.w, accp.w);
        accn.x = fmaf(tn, qv.x, accn.x); accn.y = fmaf(tn, qv.y, accn.y);
        accn.z = fmaf(tn, qv.z, accn.z); accn.w = fmaf(tn, qv.w, accn.w);
    }
    #pragma unroll
    for (int off = 16; off <= 32; off <<= 1) {
        accp.x += __shfl_xor(accp.x, off, 64); accp.y += __shfl_xor(accp.y, off, 64);
        accp.z += __shfl_xor(accp.z, off, 64); accp.w += __shfl_xor(accp.w, off, 64);
        accn.x += __shfl_xor(accn.x, off, 64); accn.y += __shfl_xor(accn.y, off, 64);
        accn.z += __shfl_xor(accn.z, off, 64); accn.w += __shfl_xor(accn.w, off, 64);
    }
    if (lo == 0) {
        *(float4*)&redp[w][e4 * 4] = accp;
        *(float4*)&redn[w][e4 * 4] = accn;
    }
    __syncthreads();
    if (tid < 64) {
        atomicAdd(&qp[bh * NE + tid], redp[0][tid] + redp[1][tid] + redp[2][tid] + redp[3][tid]);
    } else if (tid < 128) {
        int e = tid - 64;
        atomicAdd(&qn[bh * NE + e], redn[0][e] + redn[1][e] + redn[2][e] + redn[3][e]);
    }
}

// Attention kernel v7: per (b, h, s-chunk of 128). ONE barrier total.
// Phases A+B are fully wave-local: wave w computes ap/an for its own 32 s
// (s in [w*32, w*32+32)), then softmax for those same s with a per-wave wpn
// copy; the lane-pair (L, L^32) splits the 64 g and combines max/denominator
// via __shfl_xor(.,32). Only the sb -> MFMA hand-off crosses waves.
// Waves drift independently through A+B -> staggered load windows per CU.
__global__ __launch_bounds__(256, 4) void k_attn_out(
    const float* __restrict__ keys, const float* __restrict__ values,
    const float* __restrict__ sel_W,
    const float* __restrict__ qp, const float* __restrict__ qn,
    float* __restrict__ out)
{
    __shared__ short sb[NG][SROW];          // 17408 B  series bf16, [g][s]
    __shared__ float ap_l[SCH], an_l[SCH];  // 1024 B
    __shared__ float2 wpn[4][NG];           // 2048 B, per-wave copy

    int tid = threadIdx.x, blk = blockIdx.x;
    int chunk = blk & 7, bh = blk >> 3;
    int b = bh >> 3, h = bh & 7;
    int w = tid >> 6, lane = tid & 63;
    int c = lane & 15, sq = lane >> 4;
    const float scale = 0.125f;             // 1/sqrt(64)
    int s0 = chunk * SCH;

    // per-wave wpn copy (wave-local validity via lgkmcnt, no barrier)
    {
        float W = sel_W[h * NG + lane];
        wpn[w][lane] = make_float2(fmaxf(W, 0.f) * scale, fminf(W, 0.f) * scale);
    }

    const float4 qp4 = *(const float4*)(qp + bh * NE + c * 4);
    const float4 qn4 = *(const float4*)(qn + bh * NE + c * 4);

    // k tile (phase A), then v tile (phase C) — issued early, in flight
    // across A+B (no vmcnt-draining barrier until the single lgkm_barrier)
    float4 kvv[8];
    #pragma unroll
    for (int p = 0; p < 8; ++p) {
        int sl = w * 32 + p * 4 + sq;
        kvv[p] = *(const float4*)(keys + (((size_t)(b * NL + s0 + sl)) * NH + h) * NE + c * 4);
    }
    const float* vbase = values + (((size_t)(b * NL + s0)) * NH + h) * NE + 16 * w + c;
    float vregA[16], vregB[16];
    #pragma unroll
    for (int m = 0; m < 16; ++m)
        vregA[m] = vbase[(size_t)((m >> 3) * 32 + sq * 8 + (m & 7)) * (NH * NE)];
    #pragma unroll
    for (int m = 0; m < 16; ++m)
        vregB[m] = vbase[(size_t)((2 + (m >> 3)) * 32 + sq * 8 + (m & 7)) * (NH * NE)];
    __builtin_amdgcn_sched_barrier(0);

    // ---- phase A: ap/an for the wave's 32 s ----
    #pragma unroll
    for (int p = 0; p < 8; ++p) {
        int sl = w * 32 + p * 4 + sq;
        float pp = dot4(kvv[p], qp4);
        float pn = dot4(kvv[p], qn4);
        #pragma unroll
        for (int m_ = 1; m_ <= 8; m_ <<= 1) {
            pp += __shfl_xor(pp, m_, 64);
            pn += __shfl_xor(pn, m_, 64);
        }
        if (c == 0) { ap_l[sl] = pp; an_l[sl] = pn; }
    }
    lgkm_wait();   // wave-local RAW: this wave wrote [w*32, w*32+32)

    // ---- phase B: softmax, lane owns (s = w*32+(lane&31), g-half) ----
    {
        int s_ = w * 32 + (lane & 31);
        int g0 = (lane >> 5) * 32;
        float ap = ap_l[s_], an = an_l[s_];
        const float2* wv_ = &wpn[w][g0];
        float m = -1e30f;
        #pragma unroll 8
        for (int g = 0; g < 32; ++g) {
            float2 wv = wv_[g];
            m = fmaxf(m, fmaf(wv.x, ap, wv.y * an));
        }
        m = fmaxf(m, __shfl_xor(m, 32, 64));
        float d = 0.f;
        #pragma unroll 8
        for (int g = 0; g < 32; ++g) {
            float2 wv = wv_[g];
            d += __expf(fmaf(wv.x, ap, wv.y * an) - m);
        }
        d += __shfl_xor(d, 32, 64);
        float inv = 1.0f / d;
        #pragma unroll 8
        for (int g = 0; g < 32; ++g) {
            float2 wv = wv_[g];
            sb[g0 + g][s_] = f2bf(__expf(fmaf(wv.x, ap, wv.y * an) - m) * inv);
        }
    }
    lgkm_barrier();   // the ONE cross-wave barrier: sb complete

    // ---- phase C: MFMA, wave owns e-tile [16w, 16w+16) ----
    floatx4 acc[4] = {{0.f,0.f,0.f,0.f},{0.f,0.f,0.f,0.f},
                      {0.f,0.f,0.f,0.f},{0.f,0.f,0.f,0.f}};
    #pragma unroll
    for (int ks = 0; ks < 4; ++ks) {
        short8 av;
        #pragma unroll
        for (int j = 0; j < 8; ++j)
            av[j] = f2bf(ks < 2 ? vregA[ks * 8 + j] : vregB[(ks - 2) * 8 + j]);
        #pragma unroll
        for (int n = 0; n < 4; ++n) {
            short8 bv = *(const short8*)&sb[16 * n + c][ks * 32 + sq * 8];
            acc[n] = __builtin_amdgcn_mfma_f32_16x16x32_bf16(av, bv, acc[n], 0, 0, 0);
        }
    }

    // epilogue: D[row=sq*4+r][col=c]; 8 s-chunk blocks accumulate per (b,h).
    #pragma unroll
    for (int n = 0; n < 4; ++n) {
        #pragma unroll
        for (int r = 0; r < 4; ++r) {
            int e = 16 * w + sq * 4 + r;
            int g = 16 * n + c;
            atomicAdd(&out[((size_t)(b * NE + e) * NH + h) * NG + g], acc[n][r]);
        }
    }
}

extern "C" void kernel_launch(void* const* d_in, const int* in_sizes, int n_in,
                              void* d_out, int out_size, void* d_ws, size_t ws_size,
                              hipStream_t stream) {
    (void)in_sizes; (void)n_in; (void)ws_size;
    const float* queries = (const float*)d_in[0];
    const float* keys    = (const float*)d_in[1];
    const float* values  = (const float*)d_in[2];
    const float* x       = (const float*)d_in[3];
    const float* mlp_w   = (const float*)d_in[4];
    const float* mlp_b   = (const float*)d_in[5];
    const float* sel_W   = (const float*)d_in[6];
    float* out = (float*)d_out;

    // ws layout (floats): qp[8192] | qn[8192]
    float* qp_ws = (float*)d_ws;
    float* qn_ws = qp_ws + NB * NH * NE;

    hipMemsetAsync(out, 0, (size_t)out_size * sizeof(float), stream);
    hipMemsetAsync(qp_ws, 0, (size_t)2 * NB * NH * NE * sizeof(float), stream);

    k_sel_q<<<dim3(NB * NH * 8), dim3(256), 0, stream>>>(x, mlp_w, mlp_b,
                                                          queries, qp_ws, qn_ws);
    k_attn_out<<<dim3(NB * NH * 8), dim3(256), 0, stream>>>(keys, values, sel_W,
                                                            qp_ws, qn_ws, out);
}

// Round 7
// 198.350 us; speedup vs baseline: 1.7770x; 1.0065x over previous
//
#include <hip/hip_runtime.h>
#include <math.h>

#define NB 16
#define NL 1024
#define NH 8
#define NE 64
#define NWIN 1024
#define NG 64

#define SCH 128     // s-chunk per block in k_attn_out
#define SROW 136    // sb row stride in shorts (16B-aligned)

typedef __attribute__((ext_vector_type(8))) short short8;
typedef __attribute__((ext_vector_type(4))) float floatx4;

__device__ __forceinline__ short f2bf(float x) {
    unsigned u = __float_as_uint(x);
    u += 0x7fffu + ((u >> 16) & 1u);   // round-to-nearest-even
    return (short)(u >> 16);
}
__device__ __forceinline__ float dot4(float4 a, float4 b) {
    return fmaf(a.x, b.x, fmaf(a.y, b.y, fmaf(a.z, b.z, a.w * b.w)));
}
// Orders LDS traffic without draining vmcnt (keeps prefetch in flight).
__device__ __forceinline__ void lgkm_barrier() {
    asm volatile("s_waitcnt lgkmcnt(0)" ::: "memory");
    __builtin_amdgcn_s_barrier();
}
// Wave-local LDS RAW fence (no cross-wave barrier).
__device__ __forceinline__ void lgkm_wait() {
    asm volatile("s_waitcnt lgkmcnt(0)" ::: "memory");
}

// k_sel_q v7: LDS-issue halving. Each 16-lane group owns TWO rows, so the
// 8 ds_read_b128 per k-chunk feed 16 dot4s (w-operand stream amortized 2x:
// grid-wide ds_read wave-insts 524k -> 262k). 32 rows/block, grid 512.
// Both rows' x tiles (32 float4) are prefetched to registers up front
// (launch_bounds(256,2): VGPR cap 256; grid gives 2 blocks/CU regardless),
// so HBM latency overlaps the ds_read/FMA stream instead of batching.
__global__ __launch_bounds__(256, 2) void k_sel_q(
    const float* __restrict__ x, const float* __restrict__ mlp_w,
    const float* __restrict__ mlp_b, const float* __restrict__ q,
    float* __restrict__ qp, float* __restrict__ qn)
{
    __shared__ float4 w_lds[8][NWIN / 4];   // 32 KB
    __shared__ float t_lds[256];
    __shared__ float redp[4][64], redn[4][64];

    int tid = threadIdx.x;
    int blk = blockIdx.x;
    int qq = blk & 3, bh = blk >> 2;
    int b = bh >> 3, h = bh & 7;
    int w = tid >> 6, lane = tid & 63;
    int sq = lane >> 4, c = lane & 15;
    int gi = tid >> 4;                       // 16-lane group id [0,16)

    const float4* w4 = (const float4*)mlp_w;
    float4* wl = (float4*)w_lds;
    #pragma unroll
    for (int i = 0; i < 8; ++i)
        wl[tid + 256 * i] = w4[tid + 256 * i];
    __syncthreads();

    // ---- phase 1: tanh-MLP, TWO rows per 16-lane group (32 rows/block) ----
    int r0 = b * 1024 + h * 128 + qq * 32 + gi * 2;
    const float4* xr0 = (const float4*)(x + (size_t)r0 * NWIN);
    const float4* xr1 = (const float4*)(x + (size_t)(r0 + 1) * NWIN);
    float4 xv0[16], xv1[16];
    #pragma unroll
    for (int i = 0; i < 16; ++i) xv0[i] = xr0[i * 16 + c];
    #pragma unroll
    for (int i = 0; i < 16; ++i) xv1[i] = xr1[i * 16 + c];
    __builtin_amdgcn_sched_barrier(0);      // pin prefetch issue before compute

    float4 a03 = make_float4(0,0,0,0), a47 = make_float4(0,0,0,0);
    float4 d03 = make_float4(0,0,0,0), d47 = make_float4(0,0,0,0);
    #pragma unroll
    for (int i = 0; i < 16; ++i) {
        float4 w0 = w_lds[0][i * 16 + c];
        float4 w1 = w_lds[1][i * 16 + c];
        float4 w2 = w_lds[2][i * 16 + c];
        float4 w3 = w_lds[3][i * 16 + c];
        float4 w5 = w_lds[4][i * 16 + c];
        float4 w6 = w_lds[5][i * 16 + c];
        float4 w7 = w_lds[6][i * 16 + c];
        float4 w8 = w_lds[7][i * 16 + c];
        float4 xa = xv0[i], xb = xv1[i];
        a03.x += dot4(xa, w0); a03.y += dot4(xa, w1);
        a03.z += dot4(xa, w2); a03.w += dot4(xa, w3);
        a47.x += dot4(xa, w5); a47.y += dot4(xa, w6);
        a47.z += dot4(xa, w7); a47.w += dot4(xa, w8);
        d03.x += dot4(xb, w0); d03.y += dot4(xb, w1);
        d03.z += dot4(xb, w2); d03.w += dot4(xb, w3);
        d47.x += dot4(xb, w5); d47.y += dot4(xb, w6);
        d47.z += dot4(xb, w7); d47.w += dot4(xb, w8);
    }
    // 4-level butterfly within the 16-lane group (both rows)
    #pragma unroll
    for (int off = 1; off < 16; off <<= 1) {
        a03.x += __shfl_xor(a03.x, off, 64); a03.y += __shfl_xor(a03.y, off, 64);
        a03.z += __shfl_xor(a03.z, off, 64); a03.w += __shfl_xor(a03.w, off, 64);
        a47.x += __shfl_xor(a47.x, off, 64); a47.y += __shfl_xor(a47.y, off, 64);
        a47.z += __shfl_xor(a47.z, off, 64); a47.w += __shfl_xor(a47.w, off, 64);
        d03.x += __shfl_xor(d03.x, off, 64); d03.y += __shfl_xor(d03.y, off, 64);
        d03.z += __shfl_xor(d03.z, off, 64); d03.w += __shfl_xor(d03.w, off, 64);
        d47.x += __shfl_xor(d47.x, off, 64); d47.y += __shfl_xor(d47.y, off, 64);
        d47.z += __shfl_xor(d47.z, off, 64); d47.w += __shfl_xor(d47.w, off, 64);
    }
    {
        float4 b03 = *(const float4*)mlp_b;
        float4 b47 = *(const float4*)(mlp_b + 4);
        if (c == 0) {               // row 2*gi from a03/a47
            float4 t03, t47;
            t03.x = tanhf(a03.x + b03.x); t03.y = tanhf(a03.y + b03.y);
            t03.z = tanhf(a03.z + b03.z); t03.w = tanhf(a03.w + b03.w);
            t47.x = tanhf(a47.x + b47.x); t47.y = tanhf(a47.y + b47.y);
            t47.z = tanhf(a47.z + b47.z); t47.w = tanhf(a47.w + b47.w);
            *(float4*)&t_lds[(gi * 2) * 8]     = t03;
            *(float4*)&t_lds[(gi * 2) * 8 + 4] = t47;
        } else if (c == 1) {        // row 2*gi+1 from d03/d47 (all lanes hold sums)
            float4 t03, t47;
            t03.x = tanhf(d03.x + b03.x); t03.y = tanhf(d03.y + b03.y);
            t03.z = tanhf(d03.z + b03.z); t03.w = tanhf(d03.w + b03.w);
            t47.x = tanhf(d47.x + b47.x); t47.y = tanhf(d47.y + b47.y);
            t47.z = tanhf(d47.z + b47.z); t47.w = tanhf(d47.w + b47.w);
            *(float4*)&t_lds[(gi * 2 + 1) * 8]     = t03;
            *(float4*)&t_lds[(gi * 2 + 1) * 8 + 4] = t47;
        }
    }
    lgkm_wait();   // wave-local: wave w wrote rows [8w,8w+8) = l_loc [64w,+64)

    // ---- phase 2: qp/qn partial over l in [qq*256, qq*256+256) ----
    int lo = sq, e4 = c;
    float4 accp = make_float4(0,0,0,0), accn = make_float4(0,0,0,0);
    #pragma unroll
    for (int i = 0; i < 16; ++i) {
        int l_loc = w * 64 + i * 4 + lo;
        float tv = t_lds[l_loc];
        int l = qq * 256 + l_loc;
        float4 qv = *(const float4*)(q + (((size_t)(b * NL + l)) * NH + h) * NE + e4 * 4);
        float tp = fmaxf(tv, 0.f), tn = fminf(tv, 0.f);
        accp.x = fmaf(tp, qv.x, accp.x); accp.y = fmaf(tp, qv.y, accp.y);
        accp.z = fmaf(tp, qv.z, accp.z); accp.w = fmaf(tp, qv.w, accp.w);
        accn.x = fmaf(tn, qv.x, accn.x); accn.y = fmaf(tn, qv.y, accn.y);
        accn.z = fmaf(tn, qv.z, accn.z); accn.w = fmaf(tn, qv.w, accn.w);
    }
    #pragma unroll
    for (int off = 16; off <= 32; off <<= 1) {
        accp.x += __shfl_xor(accp.x, off, 64); accp.y += __shfl_xor(accp.y, off, 64);
        accp.z += __shfl_xor(accp.z, off, 64); accp.w += __shfl_xor(accp.w, off, 64);
        accn.x += __shfl_xor(accn.x, off, 64); accn.y += __shfl_xor(accn.y, off, 64);
        accn.z += __shfl_xor(accn.z, off, 64); accn.w += __shfl_xor(accn.w, off, 64);
    }
    if (lo == 0) {
        *(float4*)&redp[w][e4 * 4] = accp;
        *(float4*)&redn[w][e4 * 4] = accn;
    }
    __syncthreads();
    if (tid < 64) {
        atomicAdd(&qp[bh * NE + tid], redp[0][tid] + redp[1][tid] + redp[2][tid] + redp[3][tid]);
    } else if (tid < 128) {
        int e = tid - 64;
        atomicAdd(&qn[bh * NE + e], redn[0][e] + redn[1][e] + redn[2][e] + redn[3][e]);
    }
}

// Attention kernel v7 (unchanged from round 6): per (b, h, s-chunk of 128).
// ONE cross-wave barrier; phases A+B wave-local; k/v reg-prefetched.
__global__ __launch_bounds__(256, 4) void k_attn_out(
    const float* __restrict__ keys, const float* __restrict__ values,
    const float* __restrict__ sel_W,
    const float* __restrict__ qp, const float* __restrict__ qn,
    float* __restrict__ out)
{
    __shared__ short sb[NG][SROW];          // 17408 B  series bf16, [g][s]
    __shared__ float ap_l[SCH], an_l[SCH];  // 1024 B
    __shared__ float2 wpn[4][NG];           // 2048 B, per-wave copy

    int tid = threadIdx.x, blk = blockIdx.x;
    int chunk = blk & 7, bh = blk >> 3;
    int b = bh >> 3, h = bh & 7;
    int w = tid >> 6, lane = tid & 63;
    int c = lane & 15, sq = lane >> 4;
    const float scale = 0.125f;             // 1/sqrt(64)
    int s0 = chunk * SCH;

    // per-wave wpn copy (wave-local validity via lgkmcnt, no barrier)
    {
        float W = sel_W[h * NG + lane];
        wpn[w][lane] = make_float2(fmaxf(W, 0.f) * scale, fminf(W, 0.f) * scale);
    }

    const float4 qp4 = *(const float4*)(qp + bh * NE + c * 4);
    const float4 qn4 = *(const float4*)(qn + bh * NE + c * 4);

    // k tile (phase A), then v tile (phase C) — issued early, in flight
    // across A+B (no vmcnt-draining barrier until the single lgkm_barrier)
    float4 kvv[8];
    #pragma unroll
    for (int p = 0; p < 8; ++p) {
        int sl = w * 32 + p * 4 + sq;
        kvv[p] = *(const float4*)(keys + (((size_t)(b * NL + s0 + sl)) * NH + h) * NE + c * 4);
    }
    const float* vbase = values + (((size_t)(b * NL + s0)) * NH + h) * NE + 16 * w + c;
    float vregA[16], vregB[16];
    #pragma unroll
    for (int m = 0; m < 16; ++m)
        vregA[m] = vbase[(size_t)((m >> 3) * 32 + sq * 8 + (m & 7)) * (NH * NE)];
    #pragma unroll
    for (int m = 0; m < 16; ++m)
        vregB[m] = vbase[(size_t)((2 + (m >> 3)) * 32 + sq * 8 + (m & 7)) * (NH * NE)];
    __builtin_amdgcn_sched_barrier(0);

    // ---- phase A: ap/an for the wave's 32 s ----
    #pragma unroll
    for (int p = 0; p < 8; ++p) {
        int sl = w * 32 + p * 4 + sq;
        float pp = dot4(kvv[p], qp4);
        float pn = dot4(kvv[p], qn4);
        #pragma unroll
        for (int m_ = 1; m_ <= 8; m_ <<= 1) {
            pp += __shfl_xor(pp, m_, 64);
            pn += __shfl_xor(pn, m_, 64);
        }
        if (c == 0) { ap_l[sl] = pp; an_l[sl] = pn; }
    }
    lgkm_wait();   // wave-local RAW: this wave wrote [w*32, w*32+32)

    // ---- phase B: softmax, lane owns (s = w*32+(lane&31), g-half) ----
    {
        int s_ = w * 32 + (lane & 31);
        int g0 = (lane >> 5) * 32;
        float ap = ap_l[s_], an = an_l[s_];
        const float2* wv_ = &wpn[w][g0];
        float m = -1e30f;
        #pragma unroll 8
        for (int g = 0; g < 32; ++g) {
            float2 wv = wv_[g];
            m = fmaxf(m, fmaf(wv.x, ap, wv.y * an));
        }
        m = fmaxf(m, __shfl_xor(m, 32, 64));
        float d = 0.f;
        #pragma unroll 8
        for (int g = 0; g < 32; ++g) {
            float2 wv = wv_[g];
            d += __expf(fmaf(wv.x, ap, wv.y * an) - m);
        }
        d += __shfl_xor(d, 32, 64);
        float inv = 1.0f / d;
        #pragma unroll 8
        for (int g = 0; g < 32; ++g) {
            float2 wv = wv_[g];
            sb[g0 + g][s_] = f2bf(__expf(fmaf(wv.x, ap, wv.y * an) - m) * inv);
        }
    }
    lgkm_barrier();   // the ONE cross-wave barrier: sb complete

    // ---- phase C: MFMA, wave owns e-tile [16w, 16w+16) ----
    floatx4 acc[4] = {{0.f,0.f,0.f,0.f},{0.f,0.f,0.f,0.f},
                      {0.f,0.f,0.f,0.f},{0.f,0.f,0.f,0.f}};
    #pragma unroll
    for (int ks = 0; ks < 4; ++ks) {
        short8 av;
        #pragma unroll
        for (int j = 0; j < 8; ++j)
            av[j] = f2bf(ks < 2 ? vregA[ks * 8 + j] : vregB[(ks - 2) * 8 + j]);
        #pragma unroll
        for (int n = 0; n < 4; ++n) {
            short8 bv = *(const short8*)&sb[16 * n + c][ks * 32 + sq * 8];
            acc[n] = __builtin_amdgcn_mfma_f32_16x16x32_bf16(av, bv, acc[n], 0, 0, 0);
        }
    }

    // epilogue: D[row=sq*4+r][col=c]; 8 s-chunk blocks accumulate per (b,h).
    #pragma unroll
    for (int n = 0; n < 4; ++n) {
        #pragma unroll
        for (int r = 0; r < 4; ++r) {
            int e = 16 * w + sq * 4 + r;
            int g = 16 * n + c;
            atomicAdd(&out[((size_t)(b * NE + e) * NH + h) * NG + g], acc[n][r]);
        }
    }
}

extern "C" void kernel_launch(void* const* d_in, const int* in_sizes, int n_in,
                              void* d_out, int out_size, void* d_ws, size_t ws_size,
                              hipStream_t stream) {
    (void)in_sizes; (void)n_in; (void)ws_size;
    const float* queries = (const float*)d_in[0];
    const float* keys    = (const float*)d_in[1];
    const float* values  = (const float*)d_in[2];
    const float* x       = (const float*)d_in[3];
    const float* mlp_w   = (const float*)d_in[4];
    const float* mlp_b   = (const float*)d_in[5];
    const float* sel_W   = (const float*)d_in[6];
    float* out = (float*)d_out;

    // ws layout (floats): qp[8192] | qn[8192]
    float* qp_ws = (float*)d_ws;
    float* qn_ws = qp_ws + NB * NH * NE;

    hipMemsetAsync(out, 0, (size_t)out_size * sizeof(float), stream);
    hipMemsetAsync(qp_ws, 0, (size_t)2 * NB * NH * NE * sizeof(float), stream);

    k_sel_q<<<dim3(NB * NH * 4), dim3(256), 0, stream>>>(x, mlp_w, mlp_b,
                                                          queries, qp_ws, qn_ws);
    k_attn_out<<<dim3(NB * NH * 8), dim3(256), 0, stream>>>(keys, values, sel_W,
                                                            qp_ws, qn_ws, out);
}